// Round 16
// baseline (209.867 us; speedup 1.0000x reference)
//
#include <hip/hip_runtime.h>

typedef float  f32x4  __attribute__((ext_vector_type(4)));
typedef float  f32x4a __attribute__((ext_vector_type(4), aligned(4)));
typedef float  f32x2a __attribute__((ext_vector_type(2), aligned(4)));
typedef __bf16 bf16x8 __attribute__((ext_vector_type(8)));
typedef short  short8 __attribute__((ext_vector_type(8)));

#define F      65
#define NTT    17           // 16 D-tiles of 16 cols + 1 S-tile
#define KS3    3            // K padded (65 + bias) -> 96, 3 ksteps of 32
#define RPB    128          // rows per block (4 waves x 32 rows)
#define NEGL2E -1.4426950408889634f

__device__ __forceinline__ float fast_sigmoid(float x) {
  float e = __builtin_amdgcn_exp2f(NEGL2E * x);
  return __builtin_amdgcn_rcpf(1.0f + e);
}
template<int CTRL>
__device__ __forceinline__ float dpp_mov(float v) {
  return __builtin_bit_cast(float,
    __builtin_amdgcn_update_dpp(0, __builtin_bit_cast(int, v), CTRL, 0xF, 0xF, true));
}
__device__ __forceinline__ float reduce16(float v) {
  v += dpp_mov<0xB1>(v);                   // xor1
  v += dpp_mov<0x4E>(v);                   // xor2
  v += dpp_mov<0x141>(v);                  // xor4 (row_half_mirror)
  v += dpp_mov<0x140>(v);                  // xor8 (row_mirror)
  return v;
}

// ---- prepass: fragment-ordered bf16 W blob; D-part pre-scaled by -log2e ----
// chunk = (t*3+s)*64 + lane ; lane holds 8 bf16 of B:
//   col n = 16*t + (lane&15), k = 32*s + 8*(lane>>4) + j   (k==65 is bias row)
__global__ void prep_w(const float* __restrict__ W_S, const float* __restrict__ b_S,
                       const float* __restrict__ W_D, const float* __restrict__ b_D,
                       unsigned short* __restrict__ wsb) {
  int b = blockIdx.x;              // 0..50 = t*3+s
  int t = b / 3, s = b % 3;
  int l = threadIdx.x;
  int c = l & 15, q = l >> 4;
  short8 out;
#pragma unroll
  for (int j = 0; j < 8; ++j) {
    int k = 32 * s + 8 * q + j;
    float v = 0.0f;
    if (t < 16) {
      int n = 16 * t + c;
      if (k < F)       v = NEGL2E * W_D[n * F + k];
      else if (k == F) v = NEGL2E * b_D[n];
    } else if (c < 8) {
      if (k < F)       v = W_S[c * F + k];
      else if (k == F) v = b_S[c];
    }
    unsigned int u = __builtin_bit_cast(unsigned int, v);
    u += 0x7FFFu + ((u >> 16) & 1u);
    out[j] = (short)(u >> 16);
  }
  reinterpret_cast<short8*>(wsb)[b * 64 + l] = out;
}

// ---- main: R15 base, FULL-UNROLL D loop with compile-time offsets ---------
__launch_bounds__(256, 5)   // 5 waves/EU -> reg cap 102
__global__ void mpuf_main(const float* __restrict__ phi,
                          const unsigned short* __restrict__ wsb,
                          float* __restrict__ out_ans,
                          float* __restrict__ out_rel) {
  __shared__ float soutv[RPB][9];          // 4.6 KB : f32 souts
  __shared__ float mtrec[RPB][18];         // 9.2 KB : Mt (stride 18: b64 pairs)
  __shared__ float mlrec[RPB][17];         // 8.7 KB : Ml per (row, c)
  __shared__ float relv[RPB][8];           // 4.0 KB : |Sdelta| store bounce

  const int tid  = threadIdx.x;
  const int wave = tid >> 6;
  const int l    = tid & 63;
  const int c    = l & 15;                 // col-in-tile / row-in-A-fragment
  const int q    = l >> 4;                 // k-group / C-row quad
  const int wrow = wave * 32;
  const int brow = blockIdx.x * RPB;

  const float* prow0 = phi + (size_t)(brow + wrow + c) * F;
  const float* prow1 = prow0 + (size_t)16 * F;

  // phi loads first (HBM/L3 latency)
  f32x4a f40[4], f41[4];
#pragma unroll
  for (int s = 0; s < 2; ++s) {
    f40[2 * s]     = *reinterpret_cast<const f32x4a*>(prow0 + 32 * s + 8 * q);
    f40[2 * s + 1] = *reinterpret_cast<const f32x4a*>(prow0 + 32 * s + 8 * q + 4);
    f41[2 * s]     = *reinterpret_cast<const f32x4a*>(prow1 + 32 * s + 8 * q);
    f41[2 * s + 1] = *reinterpret_cast<const f32x4a*>(prow1 + 32 * s + 8 * q + 4);
  }
  const float a640 = prow0[64];
  const float a641 = prow1[64];

  // B: S-tile + first pair (remaining pairs hoisted by compiler, const offs)
  const short8* wsv = reinterpret_cast<const short8*>(wsb);
  short8 bS[3], bufA[3], bufB[3];
#pragma unroll
  for (int s = 0; s < 3; ++s) bS[s]   = wsv[(16 * KS3 + s) * 64 + l];
#pragma unroll
  for (int s = 0; s < 3; ++s) bufA[s] = wsv[(0 * KS3 + s) * 64 + l];
#pragma unroll
  for (int s = 0; s < 3; ++s) bufB[s] = wsv[(1 * KS3 + s) * 64 + l];

  // A -> bf16 fragments
  bf16x8 af0[3], af1[3];
#pragma unroll
  for (int s = 0; s < 2; ++s) {
    bf16x8 v0, v1;
#pragma unroll
    for (int j = 0; j < 4; ++j) {
      v0[j]     = (__bf16)f40[s * 2][j];
      v0[j + 4] = (__bf16)f40[s * 2 + 1][j];
      v1[j]     = (__bf16)f41[s * 2][j];
      v1[j + 4] = (__bf16)f41[s * 2 + 1][j];
    }
    af0[s] = v0; af1[s] = v1;
  }
  {
    bf16x8 v0 = {}, v1 = {};
    if (q == 0) {
      v0[0] = (__bf16)a640; v0[1] = (__bf16)1.0f;   // k=64 + bias row
      v1[0] = (__bf16)a641; v1[1] = (__bf16)1.0f;
    }
    af0[2] = v0; af1[2] = v1;
  }

  // ---- S tile (unscaled): Sdelta with bias folded --------------------------
  f32x4 aS0 = {}, aS1 = {};
#pragma unroll
  for (int s = 0; s < KS3; ++s) {
    bf16x8 b = __builtin_bit_cast(bf16x8, bS[s]);
    aS0 = __builtin_amdgcn_mfma_f32_16x16x32_bf16(af0[s], b, aS0, 0, 0, 0);
    aS1 = __builtin_amdgcn_mfma_f32_16x16x32_bf16(af1[s], b, aS1, 0, 0, 0);
  }
  // C layout 16x16: col = lane&15, row = (lane>>4)*4 + r
  if (c < 8) {
#pragma unroll
    for (int r = 0; r < 4; ++r) {
      const int R0 = wrow + q * 4 + r, R1 = R0 + 16;
      relv[R0][c]  = fabsf(aS0[r]);
      relv[R1][c]  = fabsf(aS1[r]);
      soutv[R0][c] = fast_sigmoid(aS0[r]);
      soutv[R1][c] = fast_sigmoid(aS1[r]);
    }
  }
  // same-wave LDS producer/consumer -> lgkmcnt-ordered, no barrier (verified).

  // ---- coalesced out_rel store: 1 KB contiguous per wave -------------------
  {
    const int row = l >> 1, half = l & 1;
    f32x4 v = *reinterpret_cast<const f32x4*>(&relv[wrow + row][half * 4]);
    *reinterpret_cast<f32x4*>(
        &out_rel[(size_t)(brow + wrow + row) * 8 + half * 4]) = v;
  }

  // ---- per-row records: Ml and Mt into LDS ---------------------------------
#pragma unroll
  for (int rr = 0; rr < 8; ++rr) {
    const int R = wrow + (rr & 4) * 4 + q * 4 + (rr & 3);
    f32x2a p01 = *reinterpret_cast<const f32x2a*>(&soutv[R][0]);
    f32x2a p23 = *reinterpret_cast<const f32x2a*>(&soutv[R][2]);
    f32x2a p45 = *reinterpret_cast<const f32x2a*>(&soutv[R][4]);
    f32x2a p67 = *reinterpret_cast<const f32x2a*>(&soutv[R][6]);
    float m = 0.99999f;
    m *= (c & 1) ? p01[0] : 1.0f - p01[0];
    m *= (c & 2) ? p01[1] : 1.0f - p01[1];
    m *= (c & 4) ? p23[0] : 1.0f - p23[0];
    m *= (c & 8) ? p23[1] : 1.0f - p23[1];
    mlrec[R][c] = m;
    float mt = (c & 1) ? p45[0] : 1.0f - p45[0];
    mt *= (c & 2) ? p45[1] : 1.0f - p45[1];
    mt *= (c & 4) ? p67[0] : 1.0f - p67[0];
    mt *= (c & 8) ? p67[1] : 1.0f - p67[1];
    mtrec[R][c] = mt;
  }

  float ans0[4] = {0, 0, 0, 0}, ans1[4] = {0, 0, 0, 0};

  // ---- D loop: FULLY UNROLLED pairs; every offset compile-time -------------
#pragma unroll
  for (int tp = 0; tp < 8; ++tp) {
    const int t0 = 2 * tp;
    const int u0 = t0 + 2, u1 = t0 + 3;    // next pair (const)

    // tile t0 from bufA, refill bufA <- u0 (skipped on last pair)
    f32x4 A0 = {}, A1 = {};
#pragma unroll
    for (int s = 0; s < KS3; ++s) {
      bf16x8 b = __builtin_bit_cast(bf16x8, bufA[s]);
      A0 = __builtin_amdgcn_mfma_f32_16x16x32_bf16(af0[s], b, A0, 0, 0, 0);
      A1 = __builtin_amdgcn_mfma_f32_16x16x32_bf16(af1[s], b, A1, 0, 0, 0);
    }
    if (tp < 7) {
#pragma unroll
      for (int s = 0; s < 3; ++s) bufA[s] = wsv[(u0 * KS3 + s) * 64 + l];
    }

    // tile t0+1 from bufB, refill bufB <- u1 (skipped on last pair)
    f32x4 B0 = {}, B1 = {};
#pragma unroll
    for (int s = 0; s < KS3; ++s) {
      bf16x8 b = __builtin_bit_cast(bf16x8, bufB[s]);
      B0 = __builtin_amdgcn_mfma_f32_16x16x32_bf16(af0[s], b, B0, 0, 0, 0);
      B1 = __builtin_amdgcn_mfma_f32_16x16x32_bf16(af1[s], b, B1, 0, 0, 0);
    }
    if (tp < 7) {
#pragma unroll
      for (int s = 0; s < 3; ++s) bufB[s] = wsv[(u1 * KS3 + s) * 64 + l];
    }

    // fused epilogue: w0/(1+E0) + w1/(1+E1) = (w0*d1 + w1*d0) / (d0*d1)
#pragma unroll
    for (int r = 0; r < 4; ++r) {
      const int R0 = wrow + q * 4 + r, R1 = R0 + 16;
      f32x2a w0 = *reinterpret_cast<const f32x2a*>(&mtrec[R0][t0]);
      f32x2a w1 = *reinterpret_cast<const f32x2a*>(&mtrec[R1][t0]);
      float d0 = 1.0f + __builtin_amdgcn_exp2f(A0[r]);
      float d1 = 1.0f + __builtin_amdgcn_exp2f(B0[r]);
      float num = fmaf(w0[0], d1, w0[1] * d0);
      ans0[r] = fmaf(num, __builtin_amdgcn_rcpf(d0 * d1), ans0[r]);
      float e0 = 1.0f + __builtin_amdgcn_exp2f(A1[r]);
      float e1 = 1.0f + __builtin_amdgcn_exp2f(B1[r]);
      float nm1 = fmaf(w1[0], e1, w1[1] * e0);
      ans1[r] = fmaf(nm1, __builtin_amdgcn_rcpf(e0 * e1), ans1[r]);
    }
  }

  // ---- apply Ml (from LDS), 16-lane DPP reduce, vectorized store -----------
  f32x4 o0, o1;
#pragma unroll
  for (int r = 0; r < 4; ++r) {
    const int R0 = wrow + q * 4 + r, R1 = R0 + 16;
    o0[r] = reduce16(mlrec[R0][c] * ans0[r]);
    o1[r] = reduce16(mlrec[R1][c] * ans1[r]);
  }
  if (c == 0) {
    *reinterpret_cast<f32x4*>(&out_ans[brow + wrow + q * 4])      = o0;
    *reinterpret_cast<f32x4*>(&out_ans[brow + wrow + 16 + q * 4]) = o1;
  }
}

extern "C" void kernel_launch(void* const* d_in, const int* in_sizes, int n_in,
                              void* d_out, int out_size, void* d_ws, size_t ws_size,
                              hipStream_t stream) {
  const float* phi = (const float*)d_in[0];
  const float* W_S = (const float*)d_in[1];
  const float* b_S = (const float*)d_in[2];
  const float* W_D = (const float*)d_in[3];
  const float* b_D = (const float*)d_in[4];
  const int rows = in_sizes[0] / F;        // 262144
  unsigned short* wsb = (unsigned short*)d_ws;   // 52224 B used
  float* out_ans = (float*)d_out;
  float* out_rel = out_ans + rows;
  hipLaunchKernelGGL(prep_w, dim3(NTT * KS3), dim3(64), 0, stream,
                     W_S, b_S, W_D, b_D, wsb);
  hipLaunchKernelGGL(mpuf_main, dim3(rows / RPB), dim3(256), 0, stream,
                     phi, wsb, out_ans, out_rel);
}

// Round 17
// 37.979 us; speedup vs baseline: 5.5259x; 5.5259x over previous
//
#include <hip/hip_runtime.h>

typedef float  f32x4  __attribute__((ext_vector_type(4)));
typedef float  f32x4a __attribute__((ext_vector_type(4), aligned(4)));
typedef float  f32x2a __attribute__((ext_vector_type(2), aligned(4)));
typedef __bf16 bf16x8 __attribute__((ext_vector_type(8)));
typedef short  short8 __attribute__((ext_vector_type(8)));

#define F      65
#define NTT    17           // 16 D-tiles of 16 cols + 1 S-tile
#define KS3    3            // K padded (65 + bias) -> 96, 3 ksteps of 32
#define RPB    128          // rows per block (4 waves x 32 rows)
#define NEGL2E -1.4426950408889634f

__device__ __forceinline__ float fast_sigmoid(float x) {
  float e = __builtin_amdgcn_exp2f(NEGL2E * x);
  return __builtin_amdgcn_rcpf(1.0f + e);
}
// acc pre-scaled by -log2e: sigmoid = rcp(1 + exp2(acc))
__device__ __forceinline__ float sig_prescaled(float a) {
  return __builtin_amdgcn_rcpf(1.0f + __builtin_amdgcn_exp2f(a));
}
template<int CTRL>
__device__ __forceinline__ float dpp_mov(float v) {
  return __builtin_bit_cast(float,
    __builtin_amdgcn_update_dpp(0, __builtin_bit_cast(int, v), CTRL, 0xF, 0xF, true));
}
__device__ __forceinline__ float reduce16(float v) {
  v += dpp_mov<0xB1>(v);                   // xor1
  v += dpp_mov<0x4E>(v);                   // xor2
  v += dpp_mov<0x141>(v);                  // xor4 (row_half_mirror)
  v += dpp_mov<0x140>(v);                  // xor8 (row_mirror)
  return v;
}

// ---- prepass: fragment-ordered bf16 W blob; D-part pre-scaled by -log2e ----
// chunk = (t*3+s)*64 + lane ; lane holds 8 bf16 of B:
//   col n = 16*t + (lane&15), k = 32*s + 8*(lane>>4) + j   (k==65 is bias row)
__global__ void prep_w(const float* __restrict__ W_S, const float* __restrict__ b_S,
                       const float* __restrict__ W_D, const float* __restrict__ b_D,
                       unsigned short* __restrict__ wsb) {
  int b = blockIdx.x;              // 0..50 = t*3+s
  int t = b / 3, s = b % 3;
  int l = threadIdx.x;
  int c = l & 15, q = l >> 4;
  short8 out;
#pragma unroll
  for (int j = 0; j < 8; ++j) {
    int k = 32 * s + 8 * q + j;
    float v = 0.0f;
    if (t < 16) {
      int n = 16 * t + c;
      if (k < F)       v = NEGL2E * W_D[n * F + k];
      else if (k == F) v = NEGL2E * b_D[n];
    } else if (c < 8) {
      if (k < F)       v = W_S[c * F + k];
      else if (k == F) v = b_S[c];
    }
    unsigned int u = __builtin_bit_cast(unsigned int, v);
    u += 0x7FFFu + ((u >> 16) & 1u);
    out[j] = (short)(u >> 16);
  }
  reinterpret_cast<short8*>(wsb)[b * 64 + l] = out;
}

// ---- main: R13 structure at 6 waves/EU (occupancy probe) -------------------
__launch_bounds__(256, 6)   // 6 waves/EU -> unified reg cap 85; R13 live ~65
__global__ void mpuf_main(const float* __restrict__ phi,
                          const unsigned short* __restrict__ wsb,
                          float* __restrict__ out_ans,
                          float* __restrict__ out_rel) {
  __shared__ float soutv[RPB][9];          // 4.6 KB : f32 souts
  __shared__ float mtrec[RPB][17];         // 8.7 KB : Mt per (row, t=c)
  __shared__ float mlrec[RPB][17];         // 8.7 KB : Ml per (row, c)
  __shared__ float relv[RPB][8];           // 4.0 KB : |Sdelta| store bounce

  const int tid  = threadIdx.x;
  const int wave = tid >> 6;
  const int l    = tid & 63;
  const int c    = l & 15;                 // col-in-tile / row-in-A-fragment
  const int q    = l >> 4;                 // k-group / C-row quad
  const int wrow = wave * 32;
  const int brow = blockIdx.x * RPB;
  const int tbase = blockIdx.x & 15;       // per-block tile stagger

  const float* prow0 = phi + (size_t)(brow + wrow + c) * F;
  const float* prow1 = prow0 + (size_t)16 * F;

  // phi loads first (HBM/L3 latency)
  f32x4a f40[4], f41[4];
#pragma unroll
  for (int s = 0; s < 2; ++s) {
    f40[2 * s]     = *reinterpret_cast<const f32x4a*>(prow0 + 32 * s + 8 * q);
    f40[2 * s + 1] = *reinterpret_cast<const f32x4a*>(prow0 + 32 * s + 8 * q + 4);
    f41[2 * s]     = *reinterpret_cast<const f32x4a*>(prow1 + 32 * s + 8 * q);
    f41[2 * s + 1] = *reinterpret_cast<const f32x4a*>(prow1 + 32 * s + 8 * q + 4);
  }
  const float a640 = prow0[64];
  const float a641 = prow1[64];

  // B prefetch: S-tile + first staggered D-tile
  const short8* wsv = reinterpret_cast<const short8*>(wsb);
  short8 bcur[3], bnxt[3];
#pragma unroll
  for (int s = 0; s < 3; ++s) bcur[s] = wsv[(16 * KS3 + s) * 64 + l];
#pragma unroll
  for (int s = 0; s < 3; ++s) bnxt[s] = wsv[(tbase * KS3 + s) * 64 + l];

  // A -> bf16 fragments
  bf16x8 af0[3], af1[3];
#pragma unroll
  for (int s = 0; s < 2; ++s) {
    bf16x8 v0, v1;
#pragma unroll
    for (int j = 0; j < 4; ++j) {
      v0[j]     = (__bf16)f40[s * 2][j];
      v0[j + 4] = (__bf16)f40[s * 2 + 1][j];
      v1[j]     = (__bf16)f41[s * 2][j];
      v1[j + 4] = (__bf16)f41[s * 2 + 1][j];
    }
    af0[s] = v0; af1[s] = v1;
  }
  {
    bf16x8 v0 = {}, v1 = {};
    if (q == 0) {
      v0[0] = (__bf16)a640; v0[1] = (__bf16)1.0f;   // k=64 + bias row
      v1[0] = (__bf16)a641; v1[1] = (__bf16)1.0f;
    }
    af0[2] = v0; af1[2] = v1;
  }

  // ---- S tile (unscaled): Sdelta with bias folded --------------------------
  f32x4 aS0 = {}, aS1 = {};
#pragma unroll
  for (int s = 0; s < KS3; ++s) {
    bf16x8 b = __builtin_bit_cast(bf16x8, bcur[s]);
    aS0 = __builtin_amdgcn_mfma_f32_16x16x32_bf16(af0[s], b, aS0, 0, 0, 0);
    aS1 = __builtin_amdgcn_mfma_f32_16x16x32_bf16(af1[s], b, aS1, 0, 0, 0);
  }
  // C layout 16x16: col = lane&15, row = (lane>>4)*4 + r
  if (c < 8) {
#pragma unroll
    for (int r = 0; r < 4; ++r) {
      const int R0 = wrow + q * 4 + r, R1 = R0 + 16;
      relv[R0][c]  = fabsf(aS0[r]);
      relv[R1][c]  = fabsf(aS1[r]);
      soutv[R0][c] = fast_sigmoid(aS0[r]);
      soutv[R1][c] = fast_sigmoid(aS1[r]);
    }
  }
  // same-wave LDS producer/consumer -> lgkmcnt-ordered, no barrier (verified).

  // ---- coalesced out_rel store: 1 KB contiguous per wave -------------------
  {
    const int row = l >> 1, half = l & 1;
    f32x4 v = *reinterpret_cast<const f32x4*>(&relv[wrow + row][half * 4]);
    *reinterpret_cast<f32x4*>(
        &out_rel[(size_t)(brow + wrow + row) * 8 + half * 4]) = v;
  }

  // ---- per-row records: Ml and Mt into LDS ---------------------------------
#pragma unroll
  for (int rr = 0; rr < 8; ++rr) {
    const int R = wrow + (rr & 4) * 4 + q * 4 + (rr & 3);
    f32x2a p01 = *reinterpret_cast<const f32x2a*>(&soutv[R][0]);
    f32x2a p23 = *reinterpret_cast<const f32x2a*>(&soutv[R][2]);
    f32x2a p45 = *reinterpret_cast<const f32x2a*>(&soutv[R][4]);
    f32x2a p67 = *reinterpret_cast<const f32x2a*>(&soutv[R][6]);
    float m = 0.99999f;
    m *= (c & 1) ? p01[0] : 1.0f - p01[0];
    m *= (c & 2) ? p01[1] : 1.0f - p01[1];
    m *= (c & 4) ? p23[0] : 1.0f - p23[0];
    m *= (c & 8) ? p23[1] : 1.0f - p23[1];
    mlrec[R][c] = m;
    float mt = (c & 1) ? p45[0] : 1.0f - p45[0];
    mt *= (c & 2) ? p45[1] : 1.0f - p45[1];
    mt *= (c & 4) ? p67[0] : 1.0f - p67[0];
    mt *= (c & 8) ? p67[1] : 1.0f - p67[1];
    mtrec[R][c] = mt;
  }

  float ans0[4] = {0, 0, 0, 0}, ans1[4] = {0, 0, 0, 0};

  // ---- D loop: staggered tiles, next-tile loads issued BEFORE MFMAs --------
#pragma unroll 1
  for (int tt = 0; tt < 16; ++tt) {
    const int t  = (tt + tbase) & 15;
    const int tn = (tt + 1 + tbase) & 15;
    short8 bt[3];
#pragma unroll
    for (int s = 0; s < 3; ++s) bt[s] = bnxt[s];       // current tile (regs)
#pragma unroll
    for (int s = 0; s < 3; ++s)                        // issue next loads NOW
      bnxt[s] = wsv[(tn * KS3 + s) * 64 + l];
    f32x4 A0 = {}, A1 = {};
#pragma unroll
    for (int s = 0; s < KS3; ++s) {
      bf16x8 b = __builtin_bit_cast(bf16x8, bt[s]);
      A0 = __builtin_amdgcn_mfma_f32_16x16x32_bf16(af0[s], b, A0, 0, 0, 0);
      A1 = __builtin_amdgcn_mfma_f32_16x16x32_bf16(af1[s], b, A1, 0, 0, 0);
    }
#pragma unroll
    for (int r = 0; r < 4; ++r) {
      const int R0 = wrow + q * 4 + r, R1 = R0 + 16;
      float w0 = mtrec[R0][t];             // broadcast per 16-lane group
      float w1 = mtrec[R1][t];
      ans0[r] = fmaf(sig_prescaled(A0[r]), w0, ans0[r]);
      ans1[r] = fmaf(sig_prescaled(A1[r]), w1, ans1[r]);
    }
  }

  // ---- apply Ml (from LDS), 16-lane DPP reduce, vectorized store -----------
  f32x4 o0, o1;
#pragma unroll
  for (int r = 0; r < 4; ++r) {
    const int R0 = wrow + q * 4 + r, R1 = R0 + 16;
    o0[r] = reduce16(mlrec[R0][c] * ans0[r]);
    o1[r] = reduce16(mlrec[R1][c] * ans1[r]);
  }
  if (c == 0) {
    *reinterpret_cast<f32x4*>(&out_ans[brow + wrow + q * 4])      = o0;
    *reinterpret_cast<f32x4*>(&out_ans[brow + wrow + 16 + q * 4]) = o1;
  }
}

extern "C" void kernel_launch(void* const* d_in, const int* in_sizes, int n_in,
                              void* d_out, int out_size, void* d_ws, size_t ws_size,
                              hipStream_t stream) {
  const float* phi = (const float*)d_in[0];
  const float* W_S = (const float*)d_in[1];
  const float* b_S = (const float*)d_in[2];
  const float* W_D = (const float*)d_in[3];
  const float* b_D = (const float*)d_in[4];
  const int rows = in_sizes[0] / F;        // 262144
  unsigned short* wsb = (unsigned short*)d_ws;   // 52224 B used
  float* out_ans = (float*)d_out;
  float* out_rel = out_ans + rows;
  hipLaunchKernelGGL(prep_w, dim3(NTT * KS3), dim3(64), 0, stream,
                     W_S, b_S, W_D, b_D, wsb);
  hipLaunchKernelGGL(mpuf_main, dim3(rows / RPB), dim3(256), 0, stream,
                     phi, wsb, out_ans, out_rel);
}

// Round 18
// 37.247 us; speedup vs baseline: 5.6344x; 1.0196x over previous
//
#include <hip/hip_runtime.h>

typedef float  f32x4  __attribute__((ext_vector_type(4)));
typedef float  f32x4a __attribute__((ext_vector_type(4), aligned(4)));
typedef __bf16 bf16x8 __attribute__((ext_vector_type(8)));
typedef short  short8 __attribute__((ext_vector_type(8)));

#define F      65
#define NTT    17           // 16 D-tiles of 16 cols + 1 S-tile
#define KS3    3            // K padded (65 + bias) -> 96, 3 ksteps of 32
#define RPB    128          // rows per block (4 waves x 32 rows)
#define NEGL2E -1.4426950408889634f

__device__ __forceinline__ float fast_sigmoid(float x) {
  float e = __builtin_amdgcn_exp2f(NEGL2E * x);
  return __builtin_amdgcn_rcpf(1.0f + e);
}
// acc pre-scaled by -log2e: sigmoid = rcp(1 + exp2(acc))
__device__ __forceinline__ float sig_prescaled(float a) {
  return __builtin_amdgcn_rcpf(1.0f + __builtin_amdgcn_exp2f(a));
}
template<int CTRL>
__device__ __forceinline__ float dpp_mov(float v) {
  return __builtin_bit_cast(float,
    __builtin_amdgcn_update_dpp(0, __builtin_bit_cast(int, v), CTRL, 0xF, 0xF, true));
}
__device__ __forceinline__ float reduce16(float v) {
  v += dpp_mov<0xB1>(v);                   // xor1
  v += dpp_mov<0x4E>(v);                   // xor2
  v += dpp_mov<0x141>(v);                  // xor4 (row_half_mirror)
  v += dpp_mov<0x140>(v);                  // xor8 (row_mirror)
  return v;
}

// ---- prepass: fragment-ordered bf16 W blob; D-part pre-scaled by -log2e ----
// chunk = (t*3+s)*64 + lane ; lane holds 8 bf16 of B:
//   col n = 16*t + (lane&15), k = 32*s + 8*(lane>>4) + j   (k==65 is bias row)
__global__ void prep_w(const float* __restrict__ W_S, const float* __restrict__ b_S,
                       const float* __restrict__ W_D, const float* __restrict__ b_D,
                       unsigned short* __restrict__ wsb) {
  int b = blockIdx.x;              // 0..50 = t*3+s
  int t = b / 3, s = b % 3;
  int l = threadIdx.x;
  int c = l & 15, q = l >> 4;
  short8 out;
#pragma unroll
  for (int j = 0; j < 8; ++j) {
    int k = 32 * s + 8 * q + j;
    float v = 0.0f;
    if (t < 16) {
      int n = 16 * t + c;
      if (k < F)       v = NEGL2E * W_D[n * F + k];
      else if (k == F) v = NEGL2E * b_D[n];
    } else if (c < 8) {
      if (k < F)       v = W_S[c * F + k];
      else if (k == F) v = b_S[c];
    }
    unsigned int u = __builtin_bit_cast(unsigned int, v);
    u += 0x7FFFu + ((u >> 16) & 1u);
    out[j] = (short)(u >> 16);
  }
  reinterpret_cast<short8*>(wsb)[b * 64 + l] = out;
}

// ---- main: R17 structure + TRANSPOSED coef tables (b128 LDS reads) ---------
__launch_bounds__(256, 6)   // 6 waves/EU -> unified reg cap 85
__global__ void mpuf_main(const float* __restrict__ phi,
                          const unsigned short* __restrict__ wsb,
                          float* __restrict__ out_ans,
                          float* __restrict__ out_rel) {
  __shared__ float soutv[RPB][12];         // 6144 B (stride 12: b128 rows)
  __shared__ float mtT[16][132];           // 8448 B : Mt[t][row] transposed
  __shared__ float mlT[16][132];           // 8448 B : Ml[c][row] transposed
  __shared__ float relv[RPB][8];           // 4096 B : |Sdelta| store bounce
  // total 27136 B -> 6 blocks/CU (162816 <= 163840)

  const int tid  = threadIdx.x;
  const int wave = tid >> 6;
  const int l    = tid & 63;
  const int c    = l & 15;                 // col-in-tile / row-in-A-fragment
  const int q    = l >> 4;                 // k-group / C-row quad
  const int wrow = wave * 32;
  const int R0b  = wrow + q * 4;           // this lane's C-row quad base
  const int brow = blockIdx.x * RPB;
  const int tbase = blockIdx.x & 15;       // per-block tile stagger

  const float* prow0 = phi + (size_t)(brow + wrow + c) * F;
  const float* prow1 = prow0 + (size_t)16 * F;

  // phi loads first (HBM/L3 latency)
  f32x4a f40[4], f41[4];
#pragma unroll
  for (int s = 0; s < 2; ++s) {
    f40[2 * s]     = *reinterpret_cast<const f32x4a*>(prow0 + 32 * s + 8 * q);
    f40[2 * s + 1] = *reinterpret_cast<const f32x4a*>(prow0 + 32 * s + 8 * q + 4);
    f41[2 * s]     = *reinterpret_cast<const f32x4a*>(prow1 + 32 * s + 8 * q);
    f41[2 * s + 1] = *reinterpret_cast<const f32x4a*>(prow1 + 32 * s + 8 * q + 4);
  }
  const float a640 = prow0[64];
  const float a641 = prow1[64];

  // B prefetch: S-tile + first staggered D-tile
  const short8* wsv = reinterpret_cast<const short8*>(wsb);
  short8 bcur[3], bnxt[3];
#pragma unroll
  for (int s = 0; s < 3; ++s) bcur[s] = wsv[(16 * KS3 + s) * 64 + l];
#pragma unroll
  for (int s = 0; s < 3; ++s) bnxt[s] = wsv[(tbase * KS3 + s) * 64 + l];

  // A -> bf16 fragments
  bf16x8 af0[3], af1[3];
#pragma unroll
  for (int s = 0; s < 2; ++s) {
    bf16x8 v0, v1;
#pragma unroll
    for (int j = 0; j < 4; ++j) {
      v0[j]     = (__bf16)f40[s * 2][j];
      v0[j + 4] = (__bf16)f40[s * 2 + 1][j];
      v1[j]     = (__bf16)f41[s * 2][j];
      v1[j + 4] = (__bf16)f41[s * 2 + 1][j];
    }
    af0[s] = v0; af1[s] = v1;
  }
  {
    bf16x8 v0 = {}, v1 = {};
    if (q == 0) {
      v0[0] = (__bf16)a640; v0[1] = (__bf16)1.0f;   // k=64 + bias row
      v1[0] = (__bf16)a641; v1[1] = (__bf16)1.0f;
    }
    af0[2] = v0; af1[2] = v1;
  }

  // ---- S tile (unscaled): Sdelta with bias folded --------------------------
  f32x4 aS0 = {}, aS1 = {};
#pragma unroll
  for (int s = 0; s < KS3; ++s) {
    bf16x8 b = __builtin_bit_cast(bf16x8, bcur[s]);
    aS0 = __builtin_amdgcn_mfma_f32_16x16x32_bf16(af0[s], b, aS0, 0, 0, 0);
    aS1 = __builtin_amdgcn_mfma_f32_16x16x32_bf16(af1[s], b, aS1, 0, 0, 0);
  }
  // C layout 16x16: col = lane&15, row = (lane>>4)*4 + r
  if (c < 8) {
#pragma unroll
    for (int r = 0; r < 4; ++r) {
      const int R0 = R0b + r, R1 = R0 + 16;
      relv[R0][c]  = fabsf(aS0[r]);
      relv[R1][c]  = fabsf(aS1[r]);
      soutv[R0][c] = fast_sigmoid(aS0[r]);
      soutv[R1][c] = fast_sigmoid(aS1[r]);
    }
  }
  // same-wave LDS producer/consumer -> lgkmcnt-ordered, no barrier (verified).

  // ---- coalesced out_rel store: 1 KB contiguous per wave -------------------
  {
    const int row = l >> 1, half = l & 1;
    f32x4 v = *reinterpret_cast<const f32x4*>(&relv[wrow + row][half * 4]);
    *reinterpret_cast<f32x4*>(
        &out_rel[(size_t)(brow + wrow + row) * 8 + half * 4]) = v;
  }

  // ---- per-row records into TRANSPOSED tables (b128 soutv reads) -----------
#pragma unroll
  for (int rr = 0; rr < 8; ++rr) {
    const int R = wrow + (rr & 4) * 4 + q * 4 + (rr & 3);
    f32x4 s03 = *reinterpret_cast<const f32x4*>(&soutv[R][0]);
    f32x4 s47 = *reinterpret_cast<const f32x4*>(&soutv[R][4]);
    float m = 0.99999f;
    m *= (c & 1) ? s03[0] : 1.0f - s03[0];
    m *= (c & 2) ? s03[1] : 1.0f - s03[1];
    m *= (c & 4) ? s03[2] : 1.0f - s03[2];
    m *= (c & 8) ? s03[3] : 1.0f - s03[3];
    mlT[c][R] = m;
    float mt = (c & 1) ? s47[0] : 1.0f - s47[0];
    mt *= (c & 2) ? s47[1] : 1.0f - s47[1];
    mt *= (c & 4) ? s47[2] : 1.0f - s47[2];
    mt *= (c & 8) ? s47[3] : 1.0f - s47[3];
    mtT[c][R] = mt;
  }

  float ans0[4] = {0, 0, 0, 0}, ans1[4] = {0, 0, 0, 0};

  // ---- D loop: staggered tiles; w via 2 b128 reads/iter (was 8 b32) --------
#pragma unroll 1
  for (int tt = 0; tt < 16; ++tt) {
    const int t  = (tt + tbase) & 15;
    const int tn = (tt + 1 + tbase) & 15;
    short8 bt[3];
#pragma unroll
    for (int s = 0; s < 3; ++s) bt[s] = bnxt[s];       // current tile (regs)
#pragma unroll
    for (int s = 0; s < 3; ++s)                        // issue next loads NOW
      bnxt[s] = wsv[(tn * KS3 + s) * 64 + l];
    // coef reads issued before MFMAs (latency hidden under them)
    f32x4 w0 = *reinterpret_cast<const f32x4*>(&mtT[t][R0b]);
    f32x4 w1 = *reinterpret_cast<const f32x4*>(&mtT[t][R0b + 16]);
    f32x4 A0 = {}, A1 = {};
#pragma unroll
    for (int s = 0; s < KS3; ++s) {
      bf16x8 b = __builtin_bit_cast(bf16x8, bt[s]);
      A0 = __builtin_amdgcn_mfma_f32_16x16x32_bf16(af0[s], b, A0, 0, 0, 0);
      A1 = __builtin_amdgcn_mfma_f32_16x16x32_bf16(af1[s], b, A1, 0, 0, 0);
    }
#pragma unroll
    for (int r = 0; r < 4; ++r) {
      ans0[r] = fmaf(sig_prescaled(A0[r]), w0[r], ans0[r]);
      ans1[r] = fmaf(sig_prescaled(A1[r]), w1[r], ans1[r]);
    }
  }

  // ---- apply Ml (2 b128 reads), 16-lane DPP reduce, vectorized store -------
  f32x4 ml0 = *reinterpret_cast<const f32x4*>(&mlT[c][R0b]);
  f32x4 ml1 = *reinterpret_cast<const f32x4*>(&mlT[c][R0b + 16]);
  f32x4 o0, o1;
#pragma unroll
  for (int r = 0; r < 4; ++r) {
    o0[r] = reduce16(ml0[r] * ans0[r]);
    o1[r] = reduce16(ml1[r] * ans1[r]);
  }
  if (c == 0) {
    *reinterpret_cast<f32x4*>(&out_ans[brow + wrow + q * 4])      = o0;
    *reinterpret_cast<f32x4*>(&out_ans[brow + wrow + 16 + q * 4]) = o1;
  }
}

extern "C" void kernel_launch(void* const* d_in, const int* in_sizes, int n_in,
                              void* d_out, int out_size, void* d_ws, size_t ws_size,
                              hipStream_t stream) {
  const float* phi = (const float*)d_in[0];
  const float* W_S = (const float*)d_in[1];
  const float* b_S = (const float*)d_in[2];
  const float* W_D = (const float*)d_in[3];
  const float* b_D = (const float*)d_in[4];
  const int rows = in_sizes[0] / F;        // 262144
  unsigned short* wsb = (unsigned short*)d_ws;   // 52224 B used
  float* out_ans = (float*)d_out;
  float* out_rel = out_ans + rows;
  hipLaunchKernelGGL(prep_w, dim3(NTT * KS3), dim3(64), 0, stream,
                     W_S, b_S, W_D, b_D, wsb);
  hipLaunchKernelGGL(mpuf_main, dim3(rows / RPB), dim3(256), 0, stream,
                     phi, wsb, out_ans, out_rel);
}

// Round 19
// 36.916 us; speedup vs baseline: 5.6850x; 1.0090x over previous
//
#include <hip/hip_runtime.h>

typedef float  f32x4  __attribute__((ext_vector_type(4)));
typedef float  f32x4a __attribute__((ext_vector_type(4), aligned(4)));
typedef __bf16 bf16x8 __attribute__((ext_vector_type(8)));
typedef short  short8 __attribute__((ext_vector_type(8)));

#define F      65
#define NTT    17           // 16 D-tiles of 16 cols + 1 S-tile
#define KS3    3            // K padded (65 + bias) -> 96, 3 ksteps of 32
#define RPB    256          // rows per block (8 waves x 32 rows)
#define NCHUNK (NTT*KS3*64) // 3264 16B chunks (52224 B)
#define NEGL2E -1.4426950408889634f

__device__ __forceinline__ float fast_sigmoid(float x) {
  float e = __builtin_amdgcn_exp2f(NEGL2E * x);
  return __builtin_amdgcn_rcpf(1.0f + e);
}
// acc pre-scaled by -log2e: sigmoid = rcp(1 + exp2(acc))
__device__ __forceinline__ float sig_prescaled(float a) {
  return __builtin_amdgcn_rcpf(1.0f + __builtin_amdgcn_exp2f(a));
}
template<int CTRL>
__device__ __forceinline__ float dpp_mov(float v) {
  return __builtin_bit_cast(float,
    __builtin_amdgcn_update_dpp(0, __builtin_bit_cast(int, v), CTRL, 0xF, 0xF, true));
}
__device__ __forceinline__ float reduce16(float v) {
  v += dpp_mov<0xB1>(v);                   // xor1
  v += dpp_mov<0x4E>(v);                   // xor2
  v += dpp_mov<0x141>(v);                  // xor4 (row_half_mirror)
  v += dpp_mov<0x140>(v);                  // xor8 (row_mirror)
  return v;
}

// ---- prepass: fragment-ordered bf16 W blob; D-part pre-scaled by -log2e ----
// chunk = (t*3+s)*64 + lane ; lane holds 8 bf16 of B:
//   col n = 16*t + (lane&15), k = 32*s + 8*(lane>>4) + j   (k==65 is bias row)
__global__ void prep_w(const float* __restrict__ W_S, const float* __restrict__ b_S,
                       const float* __restrict__ W_D, const float* __restrict__ b_D,
                       unsigned short* __restrict__ wsb) {
  int b = blockIdx.x;              // 0..50 = t*3+s
  int t = b / 3, s = b % 3;
  int l = threadIdx.x;
  int c = l & 15, q = l >> 4;
  short8 out;
#pragma unroll
  for (int j = 0; j < 8; ++j) {
    int k = 32 * s + 8 * q + j;
    float v = 0.0f;
    if (t < 16) {
      int n = 16 * t + c;
      if (k < F)       v = NEGL2E * W_D[n * F + k];
      else if (k == F) v = NEGL2E * b_D[n];
    } else if (c < 8) {
      if (k < F)       v = W_S[c * F + k];
      else if (k == F) v = b_S[c];
    }
    unsigned int u = __builtin_bit_cast(unsigned int, v);
    u += 0x7FFFu + ((u >> 16) & 1u);
    out[j] = (short)(u >> 16);
  }
  reinterpret_cast<short8*>(wsb)[b * 64 + l] = out;
}

// ---- main: LDS-resident B + lean R18 issue structure -----------------------
__launch_bounds__(512, 4)   // 4 waves/EU -> reg cap 128; LDS -> 2 blocks/CU
__global__ void mpuf_main(const float* __restrict__ phi,
                          const unsigned short* __restrict__ wsb,
                          float* __restrict__ out_ans,
                          float* __restrict__ out_rel) {
  __shared__ short8 ldsB[NCHUNK];          // 52224 B : W blob
  __shared__ float  soutv[RPB][12];        // 12288 B (stride 12: b128 rows)
  __shared__ float  mtT[16][260];          // 16640 B : Mt[t][row] transposed
  // total 81152 B -> 2 blocks/CU; rel bounce overlays mtT[0..7] (barrier-ordered)

  const int tid  = threadIdx.x;
  const int wave = tid >> 6;
  const int l    = tid & 63;
  const int c    = l & 15;                 // col-in-tile / row-in-A-fragment
  const int q    = l >> 4;                 // k-group / C-row quad
  const int wrow = wave * 32;
  const int R0b  = wrow + q * 4;           // this lane's C-row quad base
  const int brow = blockIdx.x * RPB;

  float* relbuf = &mtT[0][0];              // 2048 floats used, then reused as mtT

  const float* prow0 = phi + (size_t)(brow + wrow + c) * F;
  const float* prow1 = prow0 + (size_t)16 * F;

  // phi loads first (HBM latency hides under staging)
  f32x4a f40[4], f41[4];
#pragma unroll
  for (int s = 0; s < 2; ++s) {
    f40[2 * s]     = *reinterpret_cast<const f32x4a*>(prow0 + 32 * s + 8 * q);
    f40[2 * s + 1] = *reinterpret_cast<const f32x4a*>(prow0 + 32 * s + 8 * q + 4);
    f41[2 * s]     = *reinterpret_cast<const f32x4a*>(prow1 + 32 * s + 8 * q);
    f41[2 * s + 1] = *reinterpret_cast<const f32x4a*>(prow1 + 32 * s + 8 * q + 4);
  }
  const float a640 = prow0[64];
  const float a641 = prow1[64];

  // stage W blob -> LDS (coalesced, 7 rounds of 512 threads)
  const short8* wsv = reinterpret_cast<const short8*>(wsb);
#pragma unroll
  for (int i = 0; i < 7; ++i) {
    int idx = tid + i * 512;
    if (idx < NCHUNK) ldsB[idx] = wsv[idx];
  }

  // A -> bf16 fragments
  bf16x8 af0[3], af1[3];
#pragma unroll
  for (int s = 0; s < 2; ++s) {
    bf16x8 v0, v1;
#pragma unroll
    for (int j = 0; j < 4; ++j) {
      v0[j]     = (__bf16)f40[s * 2][j];
      v0[j + 4] = (__bf16)f40[s * 2 + 1][j];
      v1[j]     = (__bf16)f41[s * 2][j];
      v1[j + 4] = (__bf16)f41[s * 2 + 1][j];
    }
    af0[s] = v0; af1[s] = v1;
  }
  {
    bf16x8 v0 = {}, v1 = {};
    if (q == 0) {
      v0[0] = (__bf16)a640; v0[1] = (__bf16)1.0f;   // k=64 + bias row
      v1[0] = (__bf16)a641; v1[1] = (__bf16)1.0f;
    }
    af0[2] = v0; af1[2] = v1;
  }

  __syncthreads();                         // blob ready

  // ---- S tile (t=16, unscaled): Sdelta with bias folded --------------------
  f32x4 aS0 = {}, aS1 = {};
#pragma unroll
  for (int s = 0; s < KS3; ++s) {
    bf16x8 b = __builtin_bit_cast(bf16x8, ldsB[(16 * KS3 + s) * 64 + l]);
    aS0 = __builtin_amdgcn_mfma_f32_16x16x32_bf16(af0[s], b, aS0, 0, 0, 0);
    aS1 = __builtin_amdgcn_mfma_f32_16x16x32_bf16(af1[s], b, aS1, 0, 0, 0);
  }

  // prefetch D-tile 0 while S epilogue runs
  short8 bnxt[3];
#pragma unroll
  for (int s = 0; s < 3; ++s) bnxt[s] = ldsB[s * 64 + l];

  // C layout 16x16: col = lane&15, row = (lane>>4)*4 + r
  if (c < 8) {
#pragma unroll
    for (int r = 0; r < 4; ++r) {
      const int R0 = R0b + r, R1 = R0 + 16;
      relbuf[R0 * 8 + c] = fabsf(aS0[r]);
      relbuf[R1 * 8 + c] = fabsf(aS1[r]);
      soutv[R0][c] = fast_sigmoid(aS0[r]);
      soutv[R1][c] = fast_sigmoid(aS1[r]);
    }
  }
  // rel bounce read is same-wave (rows wrow..wrow+31) -> lgkm-ordered.

  // ---- coalesced out_rel store: 1 KB contiguous per wave -------------------
  {
    const int row = l >> 1, half = l & 1;
    f32x4 v = *reinterpret_cast<const f32x4*>(&relbuf[(wrow + row) * 8 + half * 4]);
    *reinterpret_cast<f32x4*>(
        &out_rel[(size_t)(brow + wrow + row) * 8 + half * 4]) = v;
  }

  __syncthreads();                         // all rel reads done before mtT writes

  // ---- per-row records: Ml in regs, Mt into transposed mtT -----------------
  float Ml0[4], Ml1[4];
#pragma unroll
  for (int rr = 0; rr < 8; ++rr) {
    const int R = wrow + (rr & 4) * 4 + q * 4 + (rr & 3);
    f32x4 s03 = *reinterpret_cast<const f32x4*>(&soutv[R][0]);
    f32x4 s47 = *reinterpret_cast<const f32x4*>(&soutv[R][4]);
    float m = 0.99999f;
    m *= (c & 1) ? s03[0] : 1.0f - s03[0];
    m *= (c & 2) ? s03[1] : 1.0f - s03[1];
    m *= (c & 4) ? s03[2] : 1.0f - s03[2];
    m *= (c & 8) ? s03[3] : 1.0f - s03[3];
    if (rr < 4) Ml0[rr & 3] = m; else Ml1[rr & 3] = m;
    float mt = (c & 1) ? s47[0] : 1.0f - s47[0];
    mt *= (c & 2) ? s47[1] : 1.0f - s47[1];
    mt *= (c & 4) ? s47[2] : 1.0f - s47[2];
    mt *= (c & 8) ? s47[3] : 1.0f - s47[3];
    mtT[c][R] = mt;
  }

  float ans0[4] = {0, 0, 0, 0}, ans1[4] = {0, 0, 0, 0};

  // ---- D loop: B from LDS (120cyc, covered by 1-ahead prefetch) ------------
#pragma unroll 1
  for (int t = 0; t < 16; ++t) {
    short8 bt[3];
#pragma unroll
    for (int s = 0; s < 3; ++s) bt[s] = bnxt[s];       // current tile
    const int tn = (t < 15) ? t + 1 : 15;
#pragma unroll
    for (int s = 0; s < 3; ++s)                        // issue next reads NOW
      bnxt[s] = ldsB[(tn * KS3 + s) * 64 + l];
    // coef reads issued before MFMAs (hidden under them)
    f32x4 w0 = *reinterpret_cast<const f32x4*>(&mtT[t][R0b]);
    f32x4 w1 = *reinterpret_cast<const f32x4*>(&mtT[t][R0b + 16]);
    f32x4 A0 = {}, A1 = {};
#pragma unroll
    for (int s = 0; s < KS3; ++s) {
      bf16x8 b = __builtin_bit_cast(bf16x8, bt[s]);
      A0 = __builtin_amdgcn_mfma_f32_16x16x32_bf16(af0[s], b, A0, 0, 0, 0);
      A1 = __builtin_amdgcn_mfma_f32_16x16x32_bf16(af1[s], b, A1, 0, 0, 0);
    }
#pragma unroll
    for (int r = 0; r < 4; ++r) {
      ans0[r] = fmaf(sig_prescaled(A0[r]), w0[r], ans0[r]);
      ans1[r] = fmaf(sig_prescaled(A1[r]), w1[r], ans1[r]);
    }
  }

  // ---- apply Ml, 16-lane DPP reduce, vectorized store ----------------------
  f32x4 o0, o1;
#pragma unroll
  for (int r = 0; r < 4; ++r) {
    o0[r] = reduce16(Ml0[r] * ans0[r]);
    o1[r] = reduce16(Ml1[r] * ans1[r]);
  }
  if (c == 0) {
    *reinterpret_cast<f32x4*>(&out_ans[brow + wrow + q * 4])      = o0;
    *reinterpret_cast<f32x4*>(&out_ans[brow + wrow + 16 + q * 4]) = o1;
  }
}

extern "C" void kernel_launch(void* const* d_in, const int* in_sizes, int n_in,
                              void* d_out, int out_size, void* d_ws, size_t ws_size,
                              hipStream_t stream) {
  const float* phi = (const float*)d_in[0];
  const float* W_S = (const float*)d_in[1];
  const float* b_S = (const float*)d_in[2];
  const float* W_D = (const float*)d_in[3];
  const float* b_D = (const float*)d_in[4];
  const int rows = in_sizes[0] / F;        // 262144
  unsigned short* wsb = (unsigned short*)d_ws;   // 52224 B used
  float* out_ans = (float*)d_out;
  float* out_rel = out_ans + rows;
  hipLaunchKernelGGL(prep_w, dim3(NTT * KS3), dim3(64), 0, stream,
                     W_S, b_S, W_D, b_D, wsb);
  hipLaunchKernelGGL(mpuf_main, dim3(rows / RPB), dim3(512), 0, stream,
                     phi, wsb, out_ans, out_rel);
}